// Round 2
// baseline (16840.977 us; speedup 1.0000x reference)
//
#include <hip/hip_runtime.h>
#include <cstdint>

#define NB 256

__device__ __forceinline__ float sigm(float x) { return 1.f / (1.f + __expf(-x)); }
__device__ __forceinline__ float tanh_(float x) { return 1.f - 2.f / (1.f + __expf(2.f * x)); }

__device__ __forceinline__ void fma4(float4& a, float s, const float4& x) {
    a.x = fmaf(s, x.x, a.x); a.y = fmaf(s, x.y, a.y);
    a.z = fmaf(s, x.z, a.z); a.w = fmaf(s, x.w, a.w);
}

// ---------------- flag-array grid barrier (no cooperative launch) ------------
// flags[1..NB-1]: per-block arrival words (distinct cachelines not needed; distinct
// words avoid RMW serialization). bar1: release word. Generation g is monotone.
// Safe under plain launch because grid == CU count at 1 block/CU occupancy.
__device__ __forceinline__ void gbar(unsigned* flags, unsigned* bar1, unsigned g) {
    const int tid = threadIdx.x, bid = blockIdx.x;
    __threadfence();     // each thread drains its stores to device scope
    __syncthreads();     // whole block's stores drained
    if (bid == 0) {
        if (tid < NB - 1) {
            while (__hip_atomic_load(&flags[tid + 1], __ATOMIC_RELAXED,
                                     __HIP_MEMORY_SCOPE_AGENT) < g)
                __builtin_amdgcn_s_sleep(1);
        }
        __syncthreads();  // all arrivals observed
        if (tid == 0)
            __hip_atomic_store(bar1, g, __ATOMIC_RELEASE, __HIP_MEMORY_SCOPE_AGENT);
    } else if (tid == 0) {
        __hip_atomic_store(&flags[bid], g, __ATOMIC_RELEASE, __HIP_MEMORY_SCOPE_AGENT);
        while (__hip_atomic_load(bar1, __ATOMIC_RELAXED,
                                 __HIP_MEMORY_SCOPE_AGENT) < g)
            __builtin_amdgcn_s_sleep(1);
    }
    __syncthreads();
    __threadfence();     // acquire side: invalidate stale cached lines
}

// ---------------- init: states into transposed [h][b] layout + zero barrier --
__global__ __launch_bounds__(256) void k_init(const float* __restrict__ h0i,
                                              const float* __restrict__ c0i,
                                              const float* __restrict__ feedi,
                                              float* h0T, float* h1T, float* c0T, float* c1T,
                                              float* feedT, unsigned* barArr) {
    int t = blockIdx.x * 256 + threadIdx.x;  // 32768 = 512*64
    if (t < NB + 1) barArr[t] = 0u;          // flags[0..255] + bar1
    int hh = t >> 6, b = t & 63;
    h0T[t]   = h0i[b * 512 + hh];
    h1T[t]   = h0i[32768 + b * 512 + hh];
    c0T[t]   = c0i[b * 512 + hh];
    c1T[t]   = c0i[32768 + b * 512 + hh];
    feedT[t] = feedi[b * 512 + hh];
}

// ---------------- in-block full-K GEMM with intra-block K-split --------------
// Block owns ROWS W-rows: row = 2*bid + (r>>1)*512 + (r&1)  (gate-interleaved
// for LSTM phases; plain 2 rows for the out phase). 512 threads decompose as
// (kq, r, b-oct): kq K-splits, reduced through LDS at the end (no grid-level
// partials). X = [seg0|seg1|seg2] of 512-k transposed [k][b] segments; seg0 ==
// nullptr means embedding gather. W = W0 (ldK0) for k<KW0 else W1 (ldK1).
// Result left in smem as Gred[kq][r][64]; caller reduces in its epilogue.
template<int ROWS, int KQ, int NCH>
__device__ __forceinline__ void gemm_block(
    float* smem, int bid, int tid,
    const float* __restrict__ W0, int ldK0, int KW0,
    const float* __restrict__ W1, int ldK1,
    const float* __restrict__ s0T, const float* __restrict__ s1T,
    const float* __restrict__ s2T,
    const float* __restrict__ emb, const int* __restrict__ toks, int tstep)
{
    static_assert(KQ * ROWS * 8 == 512, "thread decomposition");
    constexpr int KPC = 128 / KQ;           // k's per thread per chunk
    const int kq = tid / (ROWS * 8);
    const int r  = (tid >> 3) % ROWS;
    const int b0 = (tid & 7) * 8;
    const int rowg = 2 * bid + ((r >> 1) * 512) + (r & 1);
    const float* w0r = W0 + (size_t)rowg * ldK0;
    const float* w1r = W1 ? (W1 + (size_t)rowg * ldK1) : W0;
    const int kl0 = kq * KPC;

    float4 a0 = {0.f, 0.f, 0.f, 0.f}, a1 = {0.f, 0.f, 0.f, 0.f};

    for (int c = 0; c < NCH; ++c) {
        int kg0 = c << 7;
        // preload this chunk's W slice into regs (hides under staging)
        float4 wv[KPC / 4];
        {
            int kg = kg0 + kl0;
            const float* wp = (kg < KW0) ? (w0r + kg) : (w1r + (kg - KW0));
#pragma unroll
            for (int k4 = 0; k4 < KPC / 4; ++k4)
                wv[k4] = *(const float4*)(wp + k4 * 4);
        }
        __syncthreads();   // previous chunk's XT reads complete
        int seg = kg0 >> 9, ko = kg0 & 511;
        if (seg == 0 && s0T == nullptr) {
            // embedding gather + transpose: 64 rows x 128 k
            int b = tid >> 3, q = tid & 7;
            const float* er = emb + (size_t)toks[tstep * 64 + b] * 512 + ko;
#pragma unroll
            for (int j = 0; j < 4; ++j) {
                int f4 = q + j * 8;   // 0..31
                float4 v = *(const float4*)(er + f4 * 4);
                int kl = f4 << 2;
                smem[(kl + 0) * 68 + b] = v.x;
                smem[(kl + 1) * 68 + b] = v.y;
                smem[(kl + 2) * 68 + b] = v.z;
                smem[(kl + 3) * 68 + b] = v.w;
            }
        } else {
            const float* sT = (seg == 0) ? s0T : (seg == 1) ? s1T : s2T;
            const float4* src = (const float4*)(sT + (size_t)ko * 64);
#pragma unroll
            for (int j = 0; j < 4; ++j) {
                int f = tid + j * 512;  // 0..2047
                int k = f >> 4, bq = f & 15;
                *(float4*)&smem[k * 68 + bq * 4] = src[f];
            }
        }
        __syncthreads();
        const float* xb = &smem[kl0 * 68 + b0];
#pragma unroll
        for (int k4 = 0; k4 < KPC / 4; ++k4) {
            const float* x = xb + k4 * 4 * 68;
            float4 w = wv[k4];
            fma4(a0, w.x, *(const float4*)(x));
            fma4(a1, w.x, *(const float4*)(x + 4));
            fma4(a0, w.y, *(const float4*)(x + 68));
            fma4(a1, w.y, *(const float4*)(x + 72));
            fma4(a0, w.z, *(const float4*)(x + 136));
            fma4(a1, w.z, *(const float4*)(x + 140));
            fma4(a0, w.w, *(const float4*)(x + 204));
            fma4(a1, w.w, *(const float4*)(x + 208));
        }
    }
    __syncthreads();   // done reading XT; Gred aliases it
    float* gq = smem + ((size_t)(kq * ROWS + r)) * 64 + b0;
    *(float4*)gq = a0;
    *(float4*)(gq + 4) = a1;
    __syncthreads();
}

// ---------------- LSTM cell epilogue: reduce Gred + bias + activations -------
__device__ __forceinline__ void cell_epi(const float* smem, int bid, int tid,
                                         const float* __restrict__ bih,
                                         const float* __restrict__ bhh,
                                         float* __restrict__ cT, float* __restrict__ hNew,
                                         float* __restrict__ outHf, float* __restrict__ outCf,
                                         int tstep)
{
    if (tid < 128) {
        int hhl = tid >> 6, b = tid & 63;
        int hh = 2 * bid + hhl;
        float g4[4];
#pragma unroll
        for (int g = 0; g < 4; ++g) {
            int rr = g * 2 + hhl;
            float v = bih[g * 512 + hh] + bhh[g * 512 + hh];
#pragma unroll
            for (int kq = 0; kq < 8; ++kq) v += smem[(kq * 8 + rr) * 64 + b];
            g4[g] = v;
        }
        float c  = cT[hh * 64 + b];
        float cn = sigm(g4[1]) * c + sigm(g4[0]) * tanh_(g4[2]);
        float hn = sigm(g4[3]) * tanh_(cn);
        cT[hh * 64 + b]   = cn;
        hNew[hh * 64 + b] = hn;
        if (tstep == 31) { outHf[b * 512 + hh] = hn; outCf[b * 512 + hh] = cn; }
    }
}

// ---------------- per-batch attention: q = Wa@h1, softmax(q.ctx), cvec -------
__device__ __forceinline__ void attn_block(float* smem, int b, int tid,
                                           const float* __restrict__ ctx,
                                           const float* __restrict__ Wa,
                                           const float* __restrict__ h1n,
                                           float* __restrict__ cvecT,
                                           float* __restrict__ outAtt, int tstep)
{
    float* hcol = smem;          // [512]
    float* qL   = smem + 512;    // [512]
    float* pl   = smem + 1024;   // [64]
    float* scL  = smem + 1088;   // [64]
    hcol[tid] = h1n[(size_t)tid * 64 + b];
    __syncthreads();
    {   // q[h] = dot(Wa[h,:], hcol): 8 lanes per row, coalesced 128B per row
        int l = tid & 7;
#pragma unroll
        for (int rep = 0; rep < 8; ++rep) {
            int h = rep * 64 + (tid >> 3);
            const float* wr = Wa + (size_t)h * 512 + l * 4;
            float acc = 0.f;
#pragma unroll
            for (int it = 0; it < 16; ++it) {
                float4 wv = *(const float4*)(wr + it * 32);
                float4 hv = *(const float4*)&hcol[l * 4 + it * 32];
                acc = fmaf(wv.x, hv.x, acc);
                acc = fmaf(wv.y, hv.y, acc);
                acc = fmaf(wv.z, hv.z, acc);
                acc = fmaf(wv.w, hv.w, acc);
            }
            acc += __shfl_xor(acc, 1);
            acc += __shfl_xor(acc, 2);
            acc += __shfl_xor(acc, 4);
            if (l == 0) qL[h] = acc;
        }
    }
    __syncthreads();
    {   // scores[s] = dot(q, ctx[s,b,:]): 8 lanes per s
        int s = tid >> 3, l = tid & 7;
        const float* cr = ctx + ((size_t)s * 64 + b) * 512 + l * 4;
        float acc = 0.f;
#pragma unroll
        for (int it = 0; it < 16; ++it) {
            float4 cv = *(const float4*)(cr + it * 32);
            float4 qv = *(const float4*)&qL[l * 4 + it * 32];
            acc = fmaf(cv.x, qv.x, acc);
            acc = fmaf(cv.y, qv.y, acc);
            acc = fmaf(cv.z, qv.z, acc);
            acc = fmaf(cv.w, qv.w, acc);
        }
        acc += __shfl_xor(acc, 1);
        acc += __shfl_xor(acc, 2);
        acc += __shfl_xor(acc, 4);
        if (l == 0) scL[s] = acc;
    }
    __syncthreads();
    if (tid < 64) {  // softmax over 64 src positions (wave 0)
        float v = scL[tid];
        float m = v;
#pragma unroll
        for (int off = 32; off; off >>= 1) m = fmaxf(m, __shfl_xor(m, off));
        float e = __expf(v - m);
        float sum = e;
#pragma unroll
        for (int off = 32; off; off >>= 1) sum += __shfl_xor(sum, off);
        float p = e / sum;
        pl[tid] = p;
        outAtt[((size_t)tstep * 64 + b) * 64 + tid] = p;
    }
    __syncthreads();
    {   // cvec[h] = sum_s p[s] * ctx[s,b,h]
        const float* cp = ctx + (size_t)b * 512 + tid;
        float acc = 0.f;
#pragma unroll 8
        for (int s = 0; s < 64; ++s)
            acc = fmaf(pl[s], cp[(size_t)s * 32768], acc);
        cvecT[(size_t)tid * 64 + b] = acc;
    }
}

// ---------------- the whole decoder: one persistent kernel -------------------
// grid = 256 = CU count; 512 threads, 34.8 KB LDS -> 1 block/CU guaranteed
// schedulable, so all blocks are co-resident and gbar is safe under a PLAIN
// launch (no cooperative API -> no graph-capture interaction).
__global__ __launch_bounds__(512, 2) void k_fused(
    const int* __restrict__ toks, const float* __restrict__ ctx,
    const float* __restrict__ emb,
    const float* __restrict__ Wih0, const float* __restrict__ Whh0,
    const float* __restrict__ bih0, const float* __restrict__ bhh0,
    const float* __restrict__ Wih1, const float* __restrict__ Whh1,
    const float* __restrict__ bih1, const float* __restrict__ bhh1,
    const float* __restrict__ Wa, const float* __restrict__ Wout,
    float* h0T, float* h1T, float* c0T, float* c1T,
    float* feedT, float* cvecT,
    float* outMain, float* outAtt, float* outHf, float* outCf, float* outFeedf,
    unsigned* barArr)
{
    __shared__ float smem[8704];   // 34.8 KB: XT[128][68] chunk, aliased by Gred/attn
    unsigned* flags = barArr;
    unsigned* bar1  = barArr + NB;
    const int bid = blockIdx.x, tid = threadIdx.x;
    unsigned g = 0;
    int cur = 0;
    for (int t = 0; t < 32; ++t) {
        float* h0c = h0T + cur * 32768;
        float* h0n = h0T + (cur ^ 1) * 32768;
        float* h1c = h1T + cur * 32768;
        float* h1n = h1T + (cur ^ 1) * 32768;

        // Phase A: LSTM0 gates (K=1536 = [emb|feed|h0old]) + fused cell
        gemm_block<8, 8, 12>(smem, bid, tid, Wih0, 1024, 1024, Whh0, 512,
                             (const float*)nullptr, feedT, h0c, emb, toks, t);
        cell_epi(smem, bid, tid, bih0, bhh0, c0T, h0n, outHf, outCf, t);
        gbar(flags, bar1, ++g);

        // Phase B: LSTM1 gates (K=1024 = [h0new|h1old]) + fused cell
        gemm_block<8, 8, 8>(smem, bid, tid, Wih1, 512, 512, Whh1, 512,
                            h0n, h1c, (const float*)nullptr, emb, toks, t);
        cell_epi(smem, bid, tid, bih1, bhh1, c1T, h1n, outHf + 32768, outCf + 32768, t);
        gbar(flags, bar1, ++g);

        // Phase C: query + softmax + context vector; one block per batch elem
        if (bid < 64) attn_block(smem, bid, tid, ctx, Wa, h1n, cvecT, outAtt, t);
        gbar(flags, bar1, ++g);

        // Phase D: out = tanh(Wout @ [cvec|h1new]) -> outputs + next feed
        gemm_block<2, 32, 8>(smem, bid, tid, Wout, 1024, 1024,
                             (const float*)nullptr, 0,
                             cvecT, h1n, (const float*)nullptr, emb, toks, t);
        if (tid < 128) {
            int rl = tid >> 6, b = tid & 63;
            int o = 2 * bid + rl;
            float v = 0.f;
#pragma unroll
            for (int kq = 0; kq < 32; ++kq) v += smem[(kq * 2 + rl) * 64 + b];
            float ah = tanh_(v);
            outMain[((size_t)t * 64 + b) * 512 + o] = ah;
            feedT[o * 64 + b] = ah;
            if (t == 31) outFeedf[b * 512 + o] = ah;
        }
        gbar(flags, bar1, ++g);
        cur ^= 1;
    }
}

extern "C" void kernel_launch(void* const* d_in, const int* in_sizes, int n_in,
                              void* d_out, int out_size, void* d_ws, size_t ws_size,
                              hipStream_t stream) {
    const int*   toks  = (const int*)d_in[0];
    const float* ctx   = (const float*)d_in[2];
    const float* h0i   = (const float*)d_in[3];
    const float* c0i   = (const float*)d_in[4];
    const float* feedi = (const float*)d_in[5];
    const float* emb   = (const float*)d_in[6];
    const float* Wih0  = (const float*)d_in[7];
    const float* Whh0  = (const float*)d_in[8];
    const float* bih0  = (const float*)d_in[9];
    const float* bhh0  = (const float*)d_in[10];
    const float* Wih1  = (const float*)d_in[11];
    const float* Whh1  = (const float*)d_in[12];
    const float* bih1  = (const float*)d_in[13];
    const float* bhh1  = (const float*)d_in[14];
    const float* Wa    = (const float*)d_in[15];
    const float* Wout  = (const float*)d_in[16];

    // workspace (floats): h0T[2][32768] | h1T[2][32768] | c0T | c1T | feedT | cvecT | bar
    float* ws    = (float*)d_ws;
    float* h0T   = ws;                 // [0,      65536)
    float* h1T   = ws + 65536;         // [65536, 131072)
    float* c0T   = ws + 131072;
    float* c1T   = ws + 163840;
    float* feedT = ws + 196608;
    float* cvecT = ws + 229376;
    unsigned* barArr = (unsigned*)(ws + 262144);   // flags[256] + bar1

    float* out      = (float*)d_out;
    float* outMain  = out;             // [T,B,H]
    float* outAtt   = out + 1048576;   // [T,B,S]
    float* outHf    = out + 1179648;   // [L,B,H]
    float* outCf    = out + 1245184;   // [L,B,H]
    float* outFeedf = out + 1310720;   // [B,H]

    hipLaunchKernelGGL(k_init, dim3(128), dim3(256), 0, stream,
                       h0i, c0i, feedi, h0T, h1T, c0T, c1T, feedT, barArr);

    hipLaunchKernelGGL(k_fused, dim3(NB), dim3(512), 0, stream,
                       toks, ctx, emb, Wih0, Whh0, bih0, bhh0,
                       Wih1, Whh1, bih1, bhh1, Wa, Wout,
                       h0T, h1T, c0T, c1T, feedT, cvecT,
                       outMain, outAtt, outHf, outCf, outFeedf, barArr);
}

// Round 3
// 4118.340 us; speedup vs baseline: 4.0893x; 4.0893x over previous
//
#include <hip/hip_runtime.h>
#include <cstdint>

#define NB 256

__device__ __forceinline__ float sigm(float x) { return 1.f / (1.f + __expf(-x)); }
__device__ __forceinline__ float tanh_(float x) { return 1.f - 2.f / (1.f + __expf(2.f * x)); }

__device__ __forceinline__ void fma4(float4& a, float s, const float4& x) {
    a.x = fmaf(s, x.x, a.x); a.y = fmaf(s, x.y, a.y);
    a.z = fmaf(s, x.z, a.z); a.w = fmaf(s, x.w, a.w);
}

// publish a float to the LLC (coherence point), bypassing L1/L2 (sc1).
__device__ __forceinline__ void pub(float* p, float v) {
    __hip_atomic_store(p, v, __ATOMIC_RELAXED, __HIP_MEMORY_SCOPE_AGENT);
}

// ---------------- grid barrier: NO cache-invalidating fences -----------------
// All cross-block data is published via sc1 stores (already at LLC once vmcnt
// drains), and consumed via write-once addresses (never stale in any cache).
// So the barrier only needs: per-wave store drain + block barrier + flags.
// flags[1..NB-1]: per-block arrival; bar1: release word. g is monotone.
__device__ __forceinline__ void gbar(unsigned* flags, unsigned* bar1, unsigned g) {
    asm volatile("s_waitcnt vmcnt(0)" ::: "memory");  // this wave's sc1 stores at LLC
    __syncthreads();                                   // whole block drained
    const int tid = threadIdx.x, bid = blockIdx.x;
    if (bid == 0) {
        if (tid > 0 && tid < NB) {
            while (__hip_atomic_load(&flags[tid], __ATOMIC_RELAXED,
                                     __HIP_MEMORY_SCOPE_AGENT) < g)
                __builtin_amdgcn_s_sleep(2);
        }
        __syncthreads();  // all arrivals observed
        if (tid == 0)
            __hip_atomic_store(bar1, g, __ATOMIC_RELAXED, __HIP_MEMORY_SCOPE_AGENT);
    } else if (tid == 0) {
        __hip_atomic_store(&flags[bid], g, __ATOMIC_RELAXED, __HIP_MEMORY_SCOPE_AGENT);
        while (__hip_atomic_load(bar1, __ATOMIC_RELAXED,
                                 __HIP_MEMORY_SCOPE_AGENT) < g)
            __builtin_amdgcn_s_sleep(2);
    }
    __syncthreads();
}

// ---------------- init: states into transposed [h][b] slot-0 arenas ----------
__global__ __launch_bounds__(256) void k_init(const float* __restrict__ h0i,
                                              const float* __restrict__ c0i,
                                              const float* __restrict__ feedi,
                                              float* h0A, float* h1A, float* c0T, float* c1T,
                                              float* feedA, unsigned* barArr) {
    int t = blockIdx.x * 256 + threadIdx.x;  // 32768 = 512*64
    if (t < NB + 1) barArr[t] = 0u;          // flags[0..255] + bar1
    int hh = t >> 6, b = t & 63;
    h0A[t]   = h0i[b * 512 + hh];
    h1A[t]   = h0i[32768 + b * 512 + hh];
    c0T[t]   = c0i[b * 512 + hh];
    c1T[t]   = c0i[32768 + b * 512 + hh];
    feedA[t] = feedi[b * 512 + hh];
}

// ---------------- in-block full-K GEMM with intra-block K-split --------------
// Block owns ROWS W-rows: row = 2*bid + (r>>1)*512 + (r&1)  (gate-interleaved
// for LSTM phases; plain 2 rows for the out phase). 512 threads decompose as
// (kq, r, b-oct). X = [seg0|seg1|seg2] of 512-k transposed [k][b] segments;
// seg0 == nullptr means embedding gather. W = W0 (ldK0) for k<KW0 else W1.
// Result left in smem as Gred[kq][r][64]; caller reduces in its epilogue.
// X segments are write-once slots published at sc1 -> regular cached float4
// loads here are coherent and L2-shared across the XCD's 32 blocks.
template<int ROWS, int KQ, int NCH>
__device__ __forceinline__ void gemm_block(
    float* smem, int bid, int tid,
    const float* __restrict__ W0, int ldK0, int KW0,
    const float* __restrict__ W1, int ldK1,
    const float* __restrict__ s0T, const float* __restrict__ s1T,
    const float* __restrict__ s2T,
    const float* __restrict__ emb, const int* __restrict__ toks, int tstep)
{
    static_assert(KQ * ROWS * 8 == 512, "thread decomposition");
    constexpr int KPC = 128 / KQ;           // k's per thread per chunk
    const int kq = tid / (ROWS * 8);
    const int r  = (tid >> 3) % ROWS;
    const int b0 = (tid & 7) * 8;
    const int rowg = 2 * bid + ((r >> 1) * 512) + (r & 1);
    const float* w0r = W0 + (size_t)rowg * ldK0;
    const float* w1r = W1 ? (W1 + (size_t)rowg * ldK1) : W0;
    const int kl0 = kq * KPC;

    float4 a0 = {0.f, 0.f, 0.f, 0.f}, a1 = {0.f, 0.f, 0.f, 0.f};

    for (int c = 0; c < NCH; ++c) {
        int kg0 = c << 7;
        // preload this chunk's W slice into regs (hides under staging)
        float4 wv[KPC / 4];
        {
            int kg = kg0 + kl0;
            const float* wp = (kg < KW0) ? (w0r + kg) : (w1r + (kg - KW0));
#pragma unroll
            for (int k4 = 0; k4 < KPC / 4; ++k4)
                wv[k4] = *(const float4*)(wp + k4 * 4);
        }
        __syncthreads();   // previous chunk's XT reads complete
        int seg = kg0 >> 9, ko = kg0 & 511;
        if (seg == 0 && s0T == nullptr) {
            // embedding gather + transpose: 64 rows x 128 k
            int b = tid >> 3, q = tid & 7;
            const float* er = emb + (size_t)toks[tstep * 64 + b] * 512 + ko;
#pragma unroll
            for (int j = 0; j < 4; ++j) {
                int f4 = q + j * 8;   // 0..31
                float4 v = *(const float4*)(er + f4 * 4);
                int kl = f4 << 2;
                smem[(kl + 0) * 68 + b] = v.x;
                smem[(kl + 1) * 68 + b] = v.y;
                smem[(kl + 2) * 68 + b] = v.z;
                smem[(kl + 3) * 68 + b] = v.w;
            }
        } else {
            const float* sT = (seg == 0) ? s0T : (seg == 1) ? s1T : s2T;
            const float4* src = (const float4*)(sT + (size_t)ko * 64);
#pragma unroll
            for (int j = 0; j < 4; ++j) {
                int f = tid + j * 512;  // 0..2047
                int k = f >> 4, bq = f & 15;
                *(float4*)&smem[k * 68 + bq * 4] = src[f];
            }
        }
        __syncthreads();
        const float* xb = &smem[kl0 * 68 + b0];
#pragma unroll
        for (int k4 = 0; k4 < KPC / 4; ++k4) {
            const float* x = xb + k4 * 4 * 68;
            float4 w = wv[k4];
            fma4(a0, w.x, *(const float4*)(x));
            fma4(a1, w.x, *(const float4*)(x + 4));
            fma4(a0, w.y, *(const float4*)(x + 68));
            fma4(a1, w.y, *(const float4*)(x + 72));
            fma4(a0, w.z, *(const float4*)(x + 136));
            fma4(a1, w.z, *(const float4*)(x + 140));
            fma4(a0, w.w, *(const float4*)(x + 204));
            fma4(a1, w.w, *(const float4*)(x + 208));
        }
    }
    __syncthreads();   // done reading XT; Gred aliases it
    float* gq = smem + ((size_t)(kq * ROWS + r)) * 64 + b0;
    *(float4*)gq = a0;
    *(float4*)(gq + 4) = a1;
    __syncthreads();
}

// ---------------- LSTM cell epilogue: reduce Gred + bias + activations -------
// hNew is a fresh write-once slot: publish via sc1. c-state is block-private.
__device__ __forceinline__ void cell_epi(const float* smem, int bid, int tid,
                                         const float* __restrict__ bih,
                                         const float* __restrict__ bhh,
                                         float* __restrict__ cT, float* __restrict__ hNew,
                                         float* __restrict__ outHf, float* __restrict__ outCf,
                                         int tstep)
{
    if (tid < 128) {
        int hhl = tid >> 6, b = tid & 63;
        int hh = 2 * bid + hhl;
        float g4[4];
#pragma unroll
        for (int g = 0; g < 4; ++g) {
            int rr = g * 2 + hhl;
            float v = bih[g * 512 + hh] + bhh[g * 512 + hh];
#pragma unroll
            for (int kq = 0; kq < 8; ++kq) v += smem[(kq * 8 + rr) * 64 + b];
            g4[g] = v;
        }
        float c  = cT[hh * 64 + b];
        float cn = sigm(g4[1]) * c + sigm(g4[0]) * tanh_(g4[2]);
        float hn = sigm(g4[3]) * tanh_(cn);
        cT[hh * 64 + b] = cn;
        pub(&hNew[hh * 64 + b], hn);
        if (tstep == 31) { outHf[b * 512 + hh] = hn; outCf[b * 512 + hh] = cn; }
    }
}

// ---------------- per-batch attention: q = Wa@h1, softmax(q.ctx), cvec -------
__device__ __forceinline__ void attn_block(float* smem, int b, int tid,
                                           const float* __restrict__ ctx,
                                           const float* __restrict__ Wa,
                                           const float* __restrict__ h1n,
                                           float* __restrict__ cvecT,
                                           float* __restrict__ outAtt, int tstep)
{
    float* hcol = smem;          // [512]
    float* qL   = smem + 512;    // [512]
    float* pl   = smem + 1024;   // [64]
    float* scL  = smem + 1088;   // [64]
    hcol[tid] = h1n[(size_t)tid * 64 + b];   // write-once slot: cached load ok
    __syncthreads();
    {   // q[h] = dot(Wa[h,:], hcol): 8 lanes per row, coalesced 128B per row
        int l = tid & 7;
#pragma unroll
        for (int rep = 0; rep < 8; ++rep) {
            int h = rep * 64 + (tid >> 3);
            const float* wr = Wa + (size_t)h * 512 + l * 4;
            float acc = 0.f;
#pragma unroll
            for (int it = 0; it < 16; ++it) {
                float4 wv = *(const float4*)(wr + it * 32);
                float4 hv = *(const float4*)&hcol[l * 4 + it * 32];
                acc = fmaf(wv.x, hv.x, acc);
                acc = fmaf(wv.y, hv.y, acc);
                acc = fmaf(wv.z, hv.z, acc);
                acc = fmaf(wv.w, hv.w, acc);
            }
            acc += __shfl_xor(acc, 1);
            acc += __shfl_xor(acc, 2);
            acc += __shfl_xor(acc, 4);
            if (l == 0) qL[h] = acc;
        }
    }
    __syncthreads();
    {   // scores[s] = dot(q, ctx[s,b,:]): 8 lanes per s
        int s = tid >> 3, l = tid & 7;
        const float* cr = ctx + ((size_t)s * 64 + b) * 512 + l * 4;
        float acc = 0.f;
#pragma unroll
        for (int it = 0; it < 16; ++it) {
            float4 cv = *(const float4*)(cr + it * 32);
            float4 qv = *(const float4*)&qL[l * 4 + it * 32];
            acc = fmaf(cv.x, qv.x, acc);
            acc = fmaf(cv.y, qv.y, acc);
            acc = fmaf(cv.z, qv.z, acc);
            acc = fmaf(cv.w, qv.w, acc);
        }
        acc += __shfl_xor(acc, 1);
        acc += __shfl_xor(acc, 2);
        acc += __shfl_xor(acc, 4);
        if (l == 0) scL[s] = acc;
    }
    __syncthreads();
    if (tid < 64) {  // softmax over 64 src positions (wave 0)
        float v = scL[tid];
        float m = v;
#pragma unroll
        for (int off = 32; off; off >>= 1) m = fmaxf(m, __shfl_xor(m, off));
        float e = __expf(v - m);
        float sum = e;
#pragma unroll
        for (int off = 32; off; off >>= 1) sum += __shfl_xor(sum, off);
        float p = e / sum;
        pl[tid] = p;
        outAtt[((size_t)tstep * 64 + b) * 64 + tid] = p;
    }
    __syncthreads();
    {   // cvec[h] = sum_s p[s] * ctx[s,b,h] -> publish to write-once slot
        const float* cp = ctx + (size_t)b * 512 + tid;
        float acc = 0.f;
#pragma unroll 8
        for (int s = 0; s < 64; ++s)
            acc = fmaf(pl[s], cp[(size_t)s * 32768], acc);
        pub(&cvecT[(size_t)tid * 64 + b], acc);
    }
}

// ---------------- the whole decoder: one persistent kernel -------------------
// grid = 256 = CU count; 512 threads, 34.8 KB LDS, 1 block/CU -> co-resident,
// software barrier safe under plain launch. Cross-block state uses write-once
// per-step slots (h0/h1/feed/cvec arenas) published at sc1, so no cache
// invalidation is ever needed and weights/ctx stay L2-resident.
__global__ __launch_bounds__(512, 2) void k_fused(
    const int* __restrict__ toks, const float* __restrict__ ctx,
    const float* __restrict__ emb,
    const float* __restrict__ Wih0, const float* __restrict__ Whh0,
    const float* __restrict__ bih0, const float* __restrict__ bhh0,
    const float* __restrict__ Wih1, const float* __restrict__ Whh1,
    const float* __restrict__ bih1, const float* __restrict__ bhh1,
    const float* __restrict__ Wa, const float* __restrict__ Wout,
    float* h0A, float* h1A, float* c0T, float* c1T,
    float* feedA, float* cvecA,
    float* outMain, float* outAtt, float* outHf, float* outCf, float* outFeedf,
    unsigned* barArr)
{
    __shared__ float smem[8704];   // 34.8 KB: XT[128][68] chunk, aliased by Gred/attn
    unsigned* flags = barArr;
    unsigned* bar1  = barArr + NB;
    const int bid = blockIdx.x, tid = threadIdx.x;
    unsigned g = 0;
    for (int t = 0; t < 32; ++t) {
        const float* h0c = h0A + (size_t)t * 32768;         // written at A(t-1)/init
        float*       h0n = h0A + (size_t)(t + 1) * 32768;   // fresh slot
        const float* h1c = h1A + (size_t)t * 32768;
        float*       h1n = h1A + (size_t)(t + 1) * 32768;
        const float* fdc = feedA + (size_t)t * 32768;       // written at D(t-1)/init
        float*       fdn = feedA + (size_t)(t + 1) * 32768;
        float*       cvc = cvecA + (size_t)t * 32768;       // written at C(t)

        // Phase A: LSTM0 gates (K=1536 = [emb|feed|h0old]) + fused cell
        gemm_block<8, 8, 12>(smem, bid, tid, Wih0, 1024, 1024, Whh0, 512,
                             (const float*)nullptr, fdc, h0c, emb, toks, t);
        cell_epi(smem, bid, tid, bih0, bhh0, c0T, h0n, outHf, outCf, t);
        gbar(flags, bar1, ++g);

        // Phase B: LSTM1 gates (K=1024 = [h0new|h1old]) + fused cell
        gemm_block<8, 8, 8>(smem, bid, tid, Wih1, 512, 512, Whh1, 512,
                            h0n, h1c, (const float*)nullptr, emb, toks, t);
        cell_epi(smem, bid, tid, bih1, bhh1, c1T, h1n, outHf + 32768, outCf + 32768, t);
        gbar(flags, bar1, ++g);

        // Phase C: query + softmax + context vector; one block per batch elem
        if (bid < 64) attn_block(smem, bid, tid, ctx, Wa, h1n, cvc, outAtt, t);
        gbar(flags, bar1, ++g);

        // Phase D: out = tanh(Wout @ [cvec|h1new]) -> outputs + next feed
        gemm_block<2, 32, 8>(smem, bid, tid, Wout, 1024, 1024,
                             (const float*)nullptr, 0,
                             cvc, h1n, (const float*)nullptr, emb, toks, t);
        if (tid < 128) {
            int rl = tid >> 6, b = tid & 63;
            int o = 2 * bid + rl;
            float v = 0.f;
#pragma unroll
            for (int kq = 0; kq < 32; ++kq) v += smem[(kq * 2 + rl) * 64 + b];
            float ah = tanh_(v);
            outMain[((size_t)t * 64 + b) * 512 + o] = ah;
            pub(&fdn[o * 64 + b], ah);
            if (t == 31) outFeedf[b * 512 + o] = ah;
        }
        gbar(flags, bar1, ++g);
    }
}

extern "C" void kernel_launch(void* const* d_in, const int* in_sizes, int n_in,
                              void* d_out, int out_size, void* d_ws, size_t ws_size,
                              hipStream_t stream) {
    const int*   toks  = (const int*)d_in[0];
    const float* ctx   = (const float*)d_in[2];
    const float* h0i   = (const float*)d_in[3];
    const float* c0i   = (const float*)d_in[4];
    const float* feedi = (const float*)d_in[5];
    const float* emb   = (const float*)d_in[6];
    const float* Wih0  = (const float*)d_in[7];
    const float* Whh0  = (const float*)d_in[8];
    const float* bih0  = (const float*)d_in[9];
    const float* bhh0  = (const float*)d_in[10];
    const float* Wih1  = (const float*)d_in[11];
    const float* Whh1  = (const float*)d_in[12];
    const float* bih1  = (const float*)d_in[13];
    const float* bhh1  = (const float*)d_in[14];
    const float* Wa    = (const float*)d_in[15];
    const float* Wout  = (const float*)d_in[16];

    // workspace (floats), write-once arenas (33 slots of 32768 for h0/h1/feed,
    // 32 for cvec) + block-private c-state + barrier flags. Total ~17.5 MB.
    float* ws    = (float*)d_ws;
    float* h0A   = ws;                    // 33 * 32768
    float* h1A   = h0A + 33 * 32768;      // 33 * 32768
    float* feedA = h1A + 33 * 32768;      // 33 * 32768
    float* cvecA = feedA + 33 * 32768;    // 32 * 32768
    float* c0T   = cvecA + 32 * 32768;    // 32768
    float* c1T   = c0T + 32768;           // 32768
    unsigned* barArr = (unsigned*)(c1T + 32768);  // flags[256] + bar1

    float* out      = (float*)d_out;
    float* outMain  = out;             // [T,B,H]
    float* outAtt   = out + 1048576;   // [T,B,S]
    float* outHf    = out + 1179648;   // [L,B,H]
    float* outCf    = out + 1245184;   // [L,B,H]
    float* outFeedf = out + 1310720;   // [B,H]

    hipLaunchKernelGGL(k_init, dim3(128), dim3(256), 0, stream,
                       h0i, c0i, feedi, h0A, h1A, c0T, c1T, feedA, barArr);

    hipLaunchKernelGGL(k_fused, dim3(NB), dim3(512), 0, stream,
                       toks, ctx, emb, Wih0, Whh0, bih0, bhh0,
                       Wih1, Whh1, bih1, bhh1, Wa, Wout,
                       h0A, h1A, c0T, c1T, feedA, cvecA,
                       outMain, outAtt, outHf, outCf, outFeedf, barArr);
}